// Round 15
// baseline (684.687 us; speedup 1.0000x reference)
//
#include <hip/hip_runtime.h>
#include <hip/hip_cooperative_groups.h>
#include <math.h>

#define N_NODES 20000
#define N_EDGES 640000
#define HID 128
#define NPAD 20224
#define NSHARD 8
#define CGRID 1024   // cooperative grid: 4 blocks/CU guaranteed by launch_bounds(256,4)

typedef __attribute__((ext_vector_type(8))) short bf16x8;
typedef __attribute__((ext_vector_type(4))) float f32x4;
typedef __attribute__((ext_vector_type(2))) float f32x2;

#define FIX_SCALE 274877906944.0   // 2^38
#define FIX_MASK ((1ull << 48) - 1)

__device__ inline short f2bf(float f) {
    unsigned u = __builtin_bit_cast(unsigned, f);
    u += 0x7fffu + ((u >> 16) & 1u);      // RNE
    return (short)(u >> 16);
}
__device__ inline float bf2f(short s) {
    unsigned u = ((unsigned)(unsigned short)s) << 16;
    return __builtin_bit_cast(float, u);
}
__device__ inline uint2 pack_bf4(float4 f) {
    uint2 v;
    v.x = (unsigned)(unsigned short)f2bf(f.x) | ((unsigned)(unsigned short)f2bf(f.y) << 16);
    v.y = (unsigned)(unsigned short)f2bf(f.z) | ((unsigned)(unsigned short)f2bf(f.w) << 16);
    return v;
}
__device__ inline bf16x8 cvt8(float4 a0, float4 a1) {
    bf16x8 v;
    v[0] = f2bf(a0.x); v[1] = f2bf(a0.y); v[2] = f2bf(a0.z); v[3] = f2bf(a0.w);
    v[4] = f2bf(a1.x); v[5] = f2bf(a1.y); v[6] = f2bf(a1.z); v[7] = f2bf(a1.w);
    return v;
}
// fp8 e4m3 (OCP on gfx950): HW encode/decode
__device__ inline unsigned char f2fp8(float f) {
    return (unsigned char)(__builtin_amdgcn_cvt_pk_fp8_f32(f, f, 0, false) & 0xff);
}
__device__ inline float4 unpack_fp8x4(unsigned v) {
    f32x2 lo = __builtin_amdgcn_cvt_pk_f32_fp8((int)v, false);
    f32x2 hi = __builtin_amdgcn_cvt_pk_f32_fp8((int)v, true);
    return make_float4(lo[0], lo[1], hi[0], hi[1]);
}

// ---------- gather one node's fp8 rows into float4 (cols 4l..4l+3), software-pipelined ----------
__device__ inline float4 agg_node(int node, int half, int l,
                                  const unsigned char* __restrict__ xw,
                                  const int* __restrict__ rp,
                                  const int2* __restrict__ csr,
                                  const float* __restrict__ dinv) {
    float4 acc = {0.f, 0.f, 0.f, 0.f};
    if (half == 0) {   // self-loop term, counted once
        float dv = dinv[node];
        float dv2 = dv * dv;
        float4 v = unpack_fp8x4(((const unsigned*)(xw + (size_t)node * HID))[l]);
        acc.x = v.x * dv2; acc.y = v.y * dv2; acc.z = v.z * dv2; acc.w = v.w * dv2;
    }
    int j = rp[node], end = rp[node + 1];
    int n16 = (end - j) >> 4;            // full 16-edge batches
    if (n16 > 0) {
        int2 e[8];
#pragma unroll
        for (int i = 0; i < 8; i++) e[i] = csr[j + 2 * i + half];
        for (int b = 0; b + 1 < n16; b++) {
            unsigned v[8];
#pragma unroll
            for (int i = 0; i < 8; i++) v[i] = ((const unsigned*)(xw + (size_t)e[i].x * HID))[l];
            int2 en[8];                  // prefetch next batch while gathers in flight
            int jn = j + (b + 1) * 16;
#pragma unroll
            for (int i = 0; i < 8; i++) en[i] = csr[jn + 2 * i + half];
#pragma unroll
            for (int i = 0; i < 8; i++) {
                float w = __builtin_bit_cast(float, e[i].y);
                float4 f = unpack_fp8x4(v[i]);
                acc.x += f.x * w; acc.y += f.y * w; acc.z += f.z * w; acc.w += f.w * w;
            }
#pragma unroll
            for (int i = 0; i < 8; i++) e[i] = en[i];
        }
        {   // last full batch (no prefetch)
            unsigned v[8];
#pragma unroll
            for (int i = 0; i < 8; i++) v[i] = ((const unsigned*)(xw + (size_t)e[i].x * HID))[l];
#pragma unroll
            for (int i = 0; i < 8; i++) {
                float w = __builtin_bit_cast(float, e[i].y);
                float4 f = unpack_fp8x4(v[i]);
                acc.x += f.x * w; acc.y += f.y * w; acc.z += f.z * w; acc.w += f.w * w;
            }
        }
        j += n16 * 16;
    }
    if (j + 7 < end) {
        int2 e[4];
#pragma unroll
        for (int i = 0; i < 4; i++) e[i] = csr[j + 2 * i + half];
        unsigned v[4];
#pragma unroll
        for (int i = 0; i < 4; i++) v[i] = ((const unsigned*)(xw + (size_t)e[i].x * HID))[l];
#pragma unroll
        for (int i = 0; i < 4; i++) {
            float w = __builtin_bit_cast(float, e[i].y);
            float4 f = unpack_fp8x4(v[i]);
            acc.x += f.x * w; acc.y += f.y * w; acc.z += f.z * w; acc.w += f.w * w;
        }
        j += 8;
    }
    for (; j + 1 < end; j += 2) {
        int2 e0 = csr[j + half];
        float4 f = unpack_fp8x4(((const unsigned*)(xw + (size_t)e0.x * HID))[l]);
        float w0 = __builtin_bit_cast(float, e0.y);
        acc.x += f.x * w0; acc.y += f.y * w0; acc.z += f.z * w0; acc.w += f.w * w0;
    }
    if (j < end && half == 0) {
        int2 e0 = csr[j];
        float4 f = unpack_fp8x4(((const unsigned*)(xw + (size_t)e0.x * HID))[l]);
        float w0 = __builtin_bit_cast(float, e0.y);
        acc.x += f.x * w0; acc.y += f.y * w0; acc.z += f.z * w0; acc.w += f.w * w0;
    }
    acc.x += __shfl_xor(acc.x, 32);
    acc.y += __shfl_xor(acc.y, 32);
    acc.z += __shfl_xor(acc.z, 32);
    acc.w += __shfl_xor(acc.w, 32);
    return acc;
}

// ---------- K1 (cooperative): prep -> hist+gemm1 -> scan_part -> scan_final -> fill ----------
// Phases separated by grid.sync(); 1024 blocks (4/CU guaranteed).
__global__ __launch_bounds__(256, 4) void k_build(
        const float* __restrict__ W1, const float* __restrict__ W2,
        const float* __restrict__ Wu, const float* __restrict__ Wr, const float* __restrict__ Wc,
        short* WT1, short* WT2, short* WTu, short* WTr, short* WTc,
        unsigned long long* packed, int* rank,
        const int* __restrict__ dst, const float* __restrict__ ew,
        const float* __restrict__ x, unsigned char* xw,
        int* tot, int* bsum, int* rp, int* sb, float* dinv,
        const int* __restrict__ src, int2* csr) {
    cooperative_groups::grid_group grid = cooperative_groups::this_grid();
    __shared__ short As[16 * 136];   // gemm staging
    __shared__ int red[256];         // scan_part reduction
    __shared__ int smem2[256];       // scan_final scan
    __shared__ int red2[256];        // scan_final block-offset reduction
    int b = blockIdx.x;
    int tid = threadIdx.x;

    // ---- P0: weight transpose/convert (512 units) + packed zero-init (632 units) ----
    for (int u = b; u < 1144; u += CGRID) {
        if (u < 512) {
            int i = u * 256 + tid;
            if (i < 32768) {
                const float* W = (i < 16384) ? W1 : W2;
                short* T = (i < 16384) ? WT1 : WT2;
                int j = i & 16383;
                int n = j >> 7, k = j & 127;
                T[n * 128 + k] = f2bf(W[k * 128 + n]);
            } else {
                int j = i - 32768;
                const float* W = Wu; short* T = WTu;
                if (j >= 65536)      { W = Wc; T = WTc; j -= 65536; }
                else if (j >= 32768) { W = Wr; T = WTr; j -= 32768; }
                int n = j >> 8, k = j & 255;
                T[n * 256 + k] = f2bf(W[k * 128 + n]);
            }
        } else {
            int i = (u - 512) * 256 + tid;
            if (i < NSHARD * NPAD) packed[i] = 0ull;
        }
    }
    grid.sync();

    // ---- P1: hist (2500 units) + layer-1 GEMM (1250 units), co-scheduled ----
    for (int u = b; u < 3750; u += CGRID) {
        if (u < 2500) {
            int e = u * 256 + tid;
            int shard = u & (NSHARD - 1);
            int d = dst[e];
            unsigned long long add = (1ull << 48) | (unsigned long long)((double)ew[e] * FIX_SCALE);
            unsigned long long old = atomicAdd(&packed[shard * NPAD + d], add);
            rank[e] = (int)(old >> 48);
        } else {
            int r0 = (u - 2500) * 16;
            {
                int row = tid >> 4;
                int col0 = (tid & 15) * 8;
                const float* p = x + (size_t)(r0 + row) * HID + col0;
                *(bf16x8*)(&As[row * 136 + col0]) = cvt8(*(const float4*)p, *(const float4*)(p + 4));
            }
            __syncthreads();
            int wave = tid >> 6, lane = tid & 63;
            int m = lane & 15, quad = lane >> 4;
            f32x4 acc[2];
            acc[0] = (f32x4){0.f, 0.f, 0.f, 0.f};
            acc[1] = acc[0];
#pragma unroll
            for (int ks = 0; ks < 4; ks++) {
                int k0 = ks * 32 + quad * 8;
                bf16x8 a = *(const bf16x8*)(&As[m * 136 + k0]);
#pragma unroll
                for (int j = 0; j < 2; j++) {
                    int n = (wave * 2 + j) * 16 + m;
                    bf16x8 bw = *(const bf16x8*)(WT1 + n * 128 + k0);
                    acc[j] = __builtin_amdgcn_mfma_f32_16x16x32_bf16(a, bw, acc[j], 0, 0, 0);
                }
            }
#pragma unroll
            for (int j = 0; j < 2; j++) {
                int col = (wave * 2 + j) * 16 + m;
#pragma unroll
                for (int rg = 0; rg < 4; rg++) {
                    int grow = r0 + quad * 4 + rg;
                    xw[(size_t)grow * HID + col] = f2fp8(acc[j][rg]);
                }
            }
            __syncthreads();   // As reused if this block gets another gemm unit
        }
    }
    grid.sync();

    // ---- P2: scan phase 1 (blocks 0..78) ----
    if (b < 79) {
        int i = b * 256 + tid;
        int t = 0;
        if (i < N_NODES) {
#pragma unroll
            for (int s = 0; s < NSHARD; s++) t += (int)(packed[s * NPAD + i] >> 48);
            tot[i] = t;
        }
        red[tid] = t;
        __syncthreads();
        for (int off = 128; off > 0; off >>= 1) {
            if (tid < off) red[tid] += red[tid + off];
            __syncthreads();
        }
        if (tid == 0) bsum[b] = red[0];
    }
    grid.sync();

    // ---- P3: scan final -> rp, per-shard bases sb, dinv (blocks 0..78) ----
    if (b < 79) {
        red2[tid] = (tid < b) ? bsum[tid] : 0;   // b <= 78 < 256
        int i = b * 256 + tid;
        int t = (i < N_NODES) ? tot[i] : 0;
        smem2[tid] = t;
        __syncthreads();
        for (int off = 128; off > 0; off >>= 1) {
            if (tid < off) red2[tid] += red2[tid + off];
            __syncthreads();
        }
        for (int off = 1; off < 256; off <<= 1) {
            int xv = (tid >= off) ? smem2[tid - off] : 0;
            __syncthreads();
            smem2[tid] += xv;
            __syncthreads();
        }
        if (i < N_NODES) {
            int excl = smem2[tid] - t + red2[0];
            rp[i] = excl;
            if (i == N_NODES - 1) rp[N_NODES] = excl + t;
            int acc = excl;
            double deg = 1.0;   // self-loop
#pragma unroll
            for (int s = 0; s < NSHARD; s++) {
                unsigned long long p = packed[s * NPAD + i];
                sb[s * NPAD + i] = acc;
                acc += (int)(p >> 48);
                deg += (double)(p & FIX_MASK) * (1.0 / FIX_SCALE);
            }
            dinv[i] = rsqrtf((float)deg);
        }
    }
    grid.sync();

    // ---- P4: atomic-free CSR fill (2500 units) ----
    for (int u = b; u < 2500; u += CGRID) {
        int e = u * 256 + tid;
        int shard = u & (NSHARD - 1);
        int s = src[e], d = dst[e];
        int slot = sb[shard * NPAD + d] + rank[e];
        float w = dinv[s] * ew[e] * dinv[d];
        csr[slot] = make_int2(s, __builtin_bit_cast(int, w));
    }
}

// ---------- K2/K4: standalone aggregation — one wave per node, NO barriers ----------
__global__ __launch_bounds__(256) void k_agg(const unsigned char* __restrict__ xw,
                                             short* __restrict__ outb,
                                             const int* __restrict__ rp,
                                             const int2* __restrict__ csr,
                                             const float* __restrict__ dinv,
                                             const float* __restrict__ bias,
                                             int act) {
    int node = blockIdx.x * 4 + (threadIdx.x >> 6);
    int lane = threadIdx.x & 63;
    int half = lane >> 5, l = lane & 31;
    float4 acc = agg_node(node, half, l, xw, rp, csr, dinv);
    if (half == 0) {
        float4 b = ((const float4*)bias)[l];
        acc.x += b.x; acc.y += b.y; acc.z += b.z; acc.w += b.w;
        if (act == 0) {
            acc.x = fmaxf(acc.x, 0.f); acc.y = fmaxf(acc.y, 0.f);
            acc.z = fmaxf(acc.z, 0.f); acc.w = fmaxf(acc.w, 0.f);
        } else {
            acc.x = 1.f / (1.f + __expf(-acc.x)); acc.y = 1.f / (1.f + __expf(-acc.y));
            acc.z = 1.f / (1.f + __expf(-acc.z)); acc.w = 1.f / (1.f + __expf(-acc.w));
        }
        ((uint2*)(outb + (size_t)node * HID))[l] = pack_bf4(acc);
    }
}

// ---------- K3: GEMM h1(bf16) @ W2 -> xw2 (fp8), 16 rows/block ----------
__global__ __launch_bounds__(256) void k_gemm2(const short* __restrict__ Ab,
                                               const short* __restrict__ WT,
                                               unsigned char* __restrict__ Cb) {
    __shared__ short As[16 * 136];
    int tid = threadIdx.x;
    int r0 = blockIdx.x * 16;
    {
        int row = tid >> 4;
        int col0 = (tid & 15) * 8;
        *(bf16x8*)(&As[row * 136 + col0]) = *(const bf16x8*)(Ab + (size_t)(r0 + row) * HID + col0);
    }
    __syncthreads();
    int wave = tid >> 6, lane = tid & 63;
    int m = lane & 15, quad = lane >> 4;
    f32x4 acc[2];
    acc[0] = (f32x4){0.f, 0.f, 0.f, 0.f};
    acc[1] = acc[0];
#pragma unroll
    for (int ks = 0; ks < 4; ks++) {
        int k0 = ks * 32 + quad * 8;
        bf16x8 a = *(const bf16x8*)(&As[m * 136 + k0]);
#pragma unroll
        for (int j = 0; j < 2; j++) {
            int n = (wave * 2 + j) * 16 + m;
            bf16x8 b = *(const bf16x8*)(WT + n * 128 + k0);
            acc[j] = __builtin_amdgcn_mfma_f32_16x16x32_bf16(a, b, acc[j], 0, 0, 0);
        }
    }
#pragma unroll
    for (int j = 0; j < 2; j++) {
        int col = (wave * 2 + j) * 16 + m;
#pragma unroll
        for (int rg = 0; rg < 4; rg++) {
            int grow = r0 + quad * 4 + rg;
            Cb[(size_t)grow * HID + col] = f2fp8(acc[j][rg]);
        }
    }
}

// ---------- K5: fused gate: 32 rows/block (625 blocks), wave owns a 32-col strip ----------
__global__ __launch_bounds__(256) void k_gate(const short* __restrict__ xgb,
                                              const float* __restrict__ hf,
                                              const short* __restrict__ WTu, const short* __restrict__ WTr,
                                              const short* __restrict__ WTc,
                                              const float* __restrict__ pbu, const float* __restrict__ pbr,
                                              const float* __restrict__ pbc,
                                              float* __restrict__ out) {
    __shared__ short Xs[32 * 264];   // [row][0:128]=xg, [128:256]=h (later r*h)
    int tid = threadIdx.x;
    int r0 = blockIdx.x * 32;
#pragma unroll
    for (int i = 0; i < 4; i++) {
        int c = tid + i * 256;       // 1024 bf16x8 chunks
        int row = c >> 5;
        int col0 = (c & 31) * 8;
        int grow = r0 + row;
        bf16x8 v;
        if (col0 < 128) {
            v = *(const bf16x8*)(xgb + (size_t)grow * HID + col0);
        } else {
            const float* p = hf + (size_t)grow * HID + (col0 - 128);
            v = cvt8(*(const float4*)p, *(const float4*)(p + 4));
        }
        *(bf16x8*)(&Xs[row * 264 + col0]) = v;
    }
    __syncthreads();
    int wave = tid >> 6, lane = tid & 63;
    int m = lane & 15, quad = lane >> 4;
    f32x4 au[2][2], ar[2][2];
#pragma unroll
    for (int j = 0; j < 2; j++)
#pragma unroll
        for (int rt = 0; rt < 2; rt++) { au[j][rt] = (f32x4){0.f, 0.f, 0.f, 0.f}; ar[j][rt] = au[j][rt]; }
#pragma unroll
    for (int ks = 0; ks < 8; ks++) {
        int k0 = ks * 32 + quad * 8;
        bf16x8 a0 = *(const bf16x8*)(&Xs[m * 264 + k0]);            // row-tile 0
        bf16x8 a1 = *(const bf16x8*)(&Xs[(16 + m) * 264 + k0]);     // row-tile 1
#pragma unroll
        for (int j = 0; j < 2; j++) {
            int n = (wave * 2 + j) * 16 + m;
            bf16x8 bu_f = *(const bf16x8*)(WTu + n * 256 + k0);
            au[j][0] = __builtin_amdgcn_mfma_f32_16x16x32_bf16(a0, bu_f, au[j][0], 0, 0, 0);
            au[j][1] = __builtin_amdgcn_mfma_f32_16x16x32_bf16(a1, bu_f, au[j][1], 0, 0, 0);
            bf16x8 br_f = *(const bf16x8*)(WTr + n * 256 + k0);
            ar[j][0] = __builtin_amdgcn_mfma_f32_16x16x32_bf16(a0, br_f, ar[j][0], 0, 0, 0);
            ar[j][1] = __builtin_amdgcn_mfma_f32_16x16x32_bf16(a1, br_f, ar[j][1], 0, 0, 0);
        }
    }
    __syncthreads();   // phase-1 reads of the h half must finish before overwrite
#pragma unroll
    for (int j = 0; j < 2; j++) {
        int col = (wave * 2 + j) * 16 + m;
        float brv = pbr[col];
#pragma unroll
        for (int rt = 0; rt < 2; rt++) {
#pragma unroll
            for (int rg = 0; rg < 4; rg++) {
                int trow = rt * 16 + quad * 4 + rg;
                float rv = 1.f / (1.f + __expf(-(ar[j][rt][rg] + brv)));
                float hv = bf2f(Xs[trow * 264 + 128 + col]);
                Xs[trow * 264 + 128 + col] = f2bf(rv * hv);
            }
        }
    }
    __syncthreads();
    f32x4 ac[2][2];
#pragma unroll
    for (int j = 0; j < 2; j++)
#pragma unroll
        for (int rt = 0; rt < 2; rt++) ac[j][rt] = (f32x4){0.f, 0.f, 0.f, 0.f};
#pragma unroll
    for (int ks = 0; ks < 8; ks++) {
        int k0 = ks * 32 + quad * 8;
        bf16x8 a0 = *(const bf16x8*)(&Xs[m * 264 + k0]);
        bf16x8 a1 = *(const bf16x8*)(&Xs[(16 + m) * 264 + k0]);
#pragma unroll
        for (int j = 0; j < 2; j++) {
            int n = (wave * 2 + j) * 16 + m;
            bf16x8 bc_f = *(const bf16x8*)(WTc + n * 256 + k0);
            ac[j][0] = __builtin_amdgcn_mfma_f32_16x16x32_bf16(a0, bc_f, ac[j][0], 0, 0, 0);
            ac[j][1] = __builtin_amdgcn_mfma_f32_16x16x32_bf16(a1, bc_f, ac[j][1], 0, 0, 0);
        }
    }
#pragma unroll
    for (int j = 0; j < 2; j++) {
        int col = (wave * 2 + j) * 16 + m;
        float buv = pbu[col], bcv = pbc[col];
#pragma unroll
        for (int rt = 0; rt < 2; rt++) {
#pragma unroll
            for (int rg = 0; rg < 4; rg++) {
                int grow = r0 + rt * 16 + quad * 4 + rg;
                float uv = 1.f / (1.f + __expf(-(au[j][rt][rg] + buv)));
                float cv = tanhf(ac[j][rt][rg] + bcv);
                float hv = hf[(size_t)grow * HID + col];
                out[(size_t)grow * HID + col] = uv * hv + (1.f - uv) * cv;
            }
        }
    }
}

extern "C" void kernel_launch(void* const* d_in, const int* in_sizes, int n_in,
                              void* d_out, int out_size, void* d_ws, size_t ws_size,
                              hipStream_t stream) {
    const float* x  = (const float*)d_in[0];
    const int*   ei = (const int*)d_in[1];
    const float* ew = (const float*)d_in[2];
    const float* h  = (const float*)d_in[3];
    const float* W1 = (const float*)d_in[4];
    const float* b1 = (const float*)d_in[5];
    const float* W2 = (const float*)d_in[6];
    const float* b2 = (const float*)d_in[7];
    const float* Wu = (const float*)d_in[8];
    const float* bu = (const float*)d_in[9];
    const float* Wr = (const float*)d_in[10];
    const float* br = (const float*)d_in[11];
    const float* Wc = (const float*)d_in[12];
    const float* bc = (const float*)d_in[13];
    const int* src = ei;
    const int* dst = ei + N_EDGES;
    float* out = (float*)d_out;

    const size_t NH = (size_t)N_NODES * HID;
    float* ws = (float*)d_ws;
    float* dinv = ws;                                            // NPAD f32
    int*   rp   = (int*)(ws + NPAD);                             // NPAD
    unsigned long long* packed = (unsigned long long*)(ws + 2 * NPAD);  // 8*NPAD u64 = 16*NPAD f32
    int*   sb   = (int*)(ws + 18 * NPAD);                        // 8*NPAD
    int*   tot  = (int*)(ws + 26 * NPAD);                        // NPAD
    int*   bsum = (int*)(ws + 27 * NPAD);                        // 128
    int*   rank = (int*)(ws + 27 * NPAD + 128);                  // N_EDGES
    int2*  csr  = (int2*)(ws + 27 * NPAD + 128 + N_EDGES);       // N_EDGES int2
    unsigned char* xw  = (unsigned char*)(ws + 27 * NPAD + 128 + 3 * N_EDGES);  // NH fp8
    unsigned char* xw2 = xw + NH;                                // NH fp8
    short* h1b = (short*)(xw2 + NH);                             // NH bf16
    short* xgb = h1b + NH;                                       // NH bf16
    short* WT1 = xgb + NH;
    short* WT2 = WT1 + 16384;
    short* WTu = WT2 + 16384;
    short* WTr = WTu + 32768;
    short* WTc = WTr + 32768;

    // K1 (cooperative): prep -> hist+gemm1 -> scan -> fill, grid.sync between phases
    void* args[] = {
        (void*)&W1, (void*)&W2, (void*)&Wu, (void*)&Wr, (void*)&Wc,
        (void*)&WT1, (void*)&WT2, (void*)&WTu, (void*)&WTr, (void*)&WTc,
        (void*)&packed, (void*)&rank, (void*)&dst, (void*)&ew,
        (void*)&x, (void*)&xw,
        (void*)&tot, (void*)&bsum, (void*)&rp, (void*)&sb, (void*)&dinv,
        (void*)&src, (void*)&csr
    };
    hipLaunchCooperativeKernel((void*)k_build, dim3(CGRID), dim3(256), args, 0, stream);

    // K2: aggregate layer 1 (ReLU) -> h1 bf16 (pipelined gather)
    k_agg<<<N_NODES / 4, 256, 0, stream>>>(xw, h1b, rp, csr, dinv, b1, 0);
    // K3: GEMM h1 @ W2 -> xw2 fp8
    k_gemm2<<<N_NODES / 16, 256, 0, stream>>>(h1b, WT2, xw2);
    // K4: aggregate layer 2 (sigmoid) -> xg bf16 (pipelined gather)
    k_agg<<<N_NODES / 4, 256, 0, stream>>>(xw2, xgb, rp, csr, dinv, b2, 1);
    // K5: fused gating -> out (32 rows/block)
    k_gate<<<N_NODES / 32, 256, 0, stream>>>(xgb, h, WTu, WTr, WTc, bu, br, bc, out);
}

// Round 16
// 220.185 us; speedup vs baseline: 3.1096x; 3.1096x over previous
//
#include <hip/hip_runtime.h>
#include <math.h>

#define N_NODES 20000
#define N_EDGES 640000
#define HID 128
#define NPAD 20224
#define NBLK 79      // ceil(N_NODES/256)
#define NSHARD 8

typedef __attribute__((ext_vector_type(8))) short bf16x8;
typedef __attribute__((ext_vector_type(4))) float f32x4;
typedef __attribute__((ext_vector_type(2))) float f32x2;

#define FIX_SCALE 274877906944.0   // 2^38
#define FIX_MASK ((1ull << 48) - 1)

__device__ inline short f2bf(float f) {
    unsigned u = __builtin_bit_cast(unsigned, f);
    u += 0x7fffu + ((u >> 16) & 1u);      // RNE
    return (short)(u >> 16);
}
__device__ inline float bf2f(short s) {
    unsigned u = ((unsigned)(unsigned short)s) << 16;
    return __builtin_bit_cast(float, u);
}
__device__ inline uint2 pack_bf4(float4 f) {
    uint2 v;
    v.x = (unsigned)(unsigned short)f2bf(f.x) | ((unsigned)(unsigned short)f2bf(f.y) << 16);
    v.y = (unsigned)(unsigned short)f2bf(f.z) | ((unsigned)(unsigned short)f2bf(f.w) << 16);
    return v;
}
__device__ inline bf16x8 cvt8(float4 a0, float4 a1) {
    bf16x8 v;
    v[0] = f2bf(a0.x); v[1] = f2bf(a0.y); v[2] = f2bf(a0.z); v[3] = f2bf(a0.w);
    v[4] = f2bf(a1.x); v[5] = f2bf(a1.y); v[6] = f2bf(a1.z); v[7] = f2bf(a1.w);
    return v;
}
// fp8 e4m3 (OCP on gfx950): HW encode/decode
__device__ inline unsigned char f2fp8(float f) {
    return (unsigned char)(__builtin_amdgcn_cvt_pk_fp8_f32(f, f, 0, false) & 0xff);
}
__device__ inline float4 unpack_fp8x4(unsigned v) {
    f32x2 lo = __builtin_amdgcn_cvt_pk_f32_fp8((int)v, false);
    f32x2 hi = __builtin_amdgcn_cvt_pk_f32_fp8((int)v, true);
    return make_float4(lo[0], lo[1], hi[0], hi[1]);
}

// ---------- gather one node's fp8 rows into float4 (cols 4l..4l+3) ----------
// Software-pipelined: while batch b's row-gathers are in flight, batch b+1's csr
// entries are being loaded (the csr->gather dependency no longer serializes).
__device__ inline float4 agg_node(int node, int half, int l,
                                  const unsigned char* __restrict__ xw,
                                  const int* __restrict__ rp,
                                  const int2* __restrict__ csr,
                                  const float* __restrict__ dinv) {
    float4 acc = {0.f, 0.f, 0.f, 0.f};
    if (half == 0) {   // self-loop term, counted once
        float dv = dinv[node];
        float dv2 = dv * dv;
        float4 v = unpack_fp8x4(((const unsigned*)(xw + (size_t)node * HID))[l]);
        acc.x = v.x * dv2; acc.y = v.y * dv2; acc.z = v.z * dv2; acc.w = v.w * dv2;
    }
    int j = rp[node], end = rp[node + 1];
    int n16 = (end - j) >> 4;            // full 16-edge batches
    if (n16 > 0) {
        int2 e[8];
#pragma unroll
        for (int i = 0; i < 8; i++) e[i] = csr[j + 2 * i + half];
        for (int b = 0; b + 1 < n16; b++) {
            unsigned v[8];
#pragma unroll
            for (int i = 0; i < 8; i++) v[i] = ((const unsigned*)(xw + (size_t)e[i].x * HID))[l];
            int2 en[8];                  // prefetch next batch while gathers in flight
            int jn = j + (b + 1) * 16;
#pragma unroll
            for (int i = 0; i < 8; i++) en[i] = csr[jn + 2 * i + half];
#pragma unroll
            for (int i = 0; i < 8; i++) {
                float w = __builtin_bit_cast(float, e[i].y);
                float4 f = unpack_fp8x4(v[i]);
                acc.x += f.x * w; acc.y += f.y * w; acc.z += f.z * w; acc.w += f.w * w;
            }
#pragma unroll
            for (int i = 0; i < 8; i++) e[i] = en[i];
        }
        {   // last full batch (no prefetch)
            unsigned v[8];
#pragma unroll
            for (int i = 0; i < 8; i++) v[i] = ((const unsigned*)(xw + (size_t)e[i].x * HID))[l];
#pragma unroll
            for (int i = 0; i < 8; i++) {
                float w = __builtin_bit_cast(float, e[i].y);
                float4 f = unpack_fp8x4(v[i]);
                acc.x += f.x * w; acc.y += f.y * w; acc.z += f.z * w; acc.w += f.w * w;
            }
        }
        j += n16 * 16;
    }
    if (j + 7 < end) {
        int2 e[4];
#pragma unroll
        for (int i = 0; i < 4; i++) e[i] = csr[j + 2 * i + half];
        unsigned v[4];
#pragma unroll
        for (int i = 0; i < 4; i++) v[i] = ((const unsigned*)(xw + (size_t)e[i].x * HID))[l];
#pragma unroll
        for (int i = 0; i < 4; i++) {
            float w = __builtin_bit_cast(float, e[i].y);
            float4 f = unpack_fp8x4(v[i]);
            acc.x += f.x * w; acc.y += f.y * w; acc.z += f.z * w; acc.w += f.w * w;
        }
        j += 8;
    }
    for (; j + 1 < end; j += 2) {
        int2 e0 = csr[j + half];
        float4 f = unpack_fp8x4(((const unsigned*)(xw + (size_t)e0.x * HID))[l]);
        float w0 = __builtin_bit_cast(float, e0.y);
        acc.x += f.x * w0; acc.y += f.y * w0; acc.z += f.z * w0; acc.w += f.w * w0;
    }
    if (j < end && half == 0) {
        int2 e0 = csr[j];
        float4 f = unpack_fp8x4(((const unsigned*)(xw + (size_t)e0.x * HID))[l]);
        float w0 = __builtin_bit_cast(float, e0.y);
        acc.x += f.x * w0; acc.y += f.y * w0; acc.z += f.z * w0; acc.w += f.w * w0;
    }
    acc.x += __shfl_xor(acc.x, 32);
    acc.y += __shfl_xor(acc.y, 32);
    acc.z += __shfl_xor(acc.z, 32);
    acc.w += __shfl_xor(acc.w, 32);
    return acc;
}

// ---------- K1: weight transpose/convert (blocks 0..511) + packed zero-init (blocks 512..) ----------
__global__ __launch_bounds__(256) void k_prep(const float* __restrict__ W1, const float* __restrict__ W2,
                                              const float* __restrict__ Wu, const float* __restrict__ Wr,
                                              const float* __restrict__ Wc,
                                              short* WT1, short* WT2, short* WTu, short* WTr, short* WTc,
                                              unsigned long long* packed) {
    int b = blockIdx.x;
    int tid = threadIdx.x;
    if (b < 512) {
        int i = b * 256 + tid;
        if (i < 32768) {
            const float* W = (i < 16384) ? W1 : W2;
            short* T = (i < 16384) ? WT1 : WT2;
            int j = i & 16383;
            int n = j >> 7, k = j & 127;
            T[n * 128 + k] = f2bf(W[k * 128 + n]);
        } else {
            int j = i - 32768;
            const float* W = Wu; short* T = WTu;
            if (j >= 65536)      { W = Wc; T = WTc; j -= 65536; }
            else if (j >= 32768) { W = Wr; T = WTr; j -= 32768; }
            int n = j >> 8, k = j & 255;
            T[n * 256 + k] = f2bf(W[k * 128 + n]);
        }
    } else {
        int i = (b - 512) * 256 + tid;
        if (i < NSHARD * NPAD) packed[i] = 0ull;
    }
}

// ---------- K2: co-scheduled hist (blocks 0..2499) + layer-1 GEMM (blocks 2500..3749) ----------
__global__ __launch_bounds__(256) void k_hist_gemm(unsigned long long* packed, int* __restrict__ rank,
                                                   const int* __restrict__ dst,
                                                   const float* __restrict__ ew,
                                                   const float* __restrict__ x,
                                                   const short* __restrict__ WT1,
                                                   unsigned char* __restrict__ xw) {
    __shared__ short As[16 * 136];
    int tid = threadIdx.x;
    if (blockIdx.x < 2500) {
        int e = blockIdx.x * 256 + tid;
        int shard = blockIdx.x & (NSHARD - 1);
        int d = dst[e];
        unsigned long long add = (1ull << 48) | (unsigned long long)((double)ew[e] * FIX_SCALE);
        unsigned long long old = atomicAdd(&packed[shard * NPAD + d], add);
        rank[e] = (int)(old >> 48);
        return;
    }
    int r0 = (blockIdx.x - 2500) * 16;
    {
        int row = tid >> 4;
        int col0 = (tid & 15) * 8;
        const float* p = x + (size_t)(r0 + row) * HID + col0;
        *(bf16x8*)(&As[row * 136 + col0]) = cvt8(*(const float4*)p, *(const float4*)(p + 4));
    }
    __syncthreads();
    int wave = tid >> 6, lane = tid & 63;
    int m = lane & 15, quad = lane >> 4;
    f32x4 acc[2];
    acc[0] = (f32x4){0.f, 0.f, 0.f, 0.f};
    acc[1] = acc[0];
#pragma unroll
    for (int ks = 0; ks < 4; ks++) {
        int k0 = ks * 32 + quad * 8;
        bf16x8 a = *(const bf16x8*)(&As[m * 136 + k0]);
#pragma unroll
        for (int j = 0; j < 2; j++) {
            int n = (wave * 2 + j) * 16 + m;
            bf16x8 b = *(const bf16x8*)(WT1 + n * 128 + k0);
            acc[j] = __builtin_amdgcn_mfma_f32_16x16x32_bf16(a, b, acc[j], 0, 0, 0);
        }
    }
#pragma unroll
    for (int j = 0; j < 2; j++) {
        int col = (wave * 2 + j) * 16 + m;
#pragma unroll
        for (int rg = 0; rg < 4; rg++) {
            int grow = r0 + quad * 4 + rg;
            xw[(size_t)grow * HID + col] = f2fp8(acc[j][rg]);
        }
    }
}

// ---------- K3: scan phase 1 ----------
__global__ __launch_bounds__(256) void k_scan_part(const unsigned long long* __restrict__ packed,
                                                   int* __restrict__ tot, int* __restrict__ bsum) {
    __shared__ int red[256];
    int tid = threadIdx.x;
    int i = blockIdx.x * 256 + tid;
    int t = 0;
    if (i < N_NODES) {
#pragma unroll
        for (int s = 0; s < NSHARD; s++) t += (int)(packed[s * NPAD + i] >> 48);
        tot[i] = t;
    }
    red[tid] = t;
    __syncthreads();
    for (int off = 128; off > 0; off >>= 1) {
        if (tid < off) red[tid] += red[tid + off];
        __syncthreads();
    }
    if (tid == 0) bsum[blockIdx.x] = red[0];
}

// ---------- K4: scan final -> rp, per-shard bases sb, dinv ----------
__global__ __launch_bounds__(256) void k_scan_final(const unsigned long long* __restrict__ packed,
                                                    const int* __restrict__ tot,
                                                    const int* __restrict__ bsum,
                                                    int* __restrict__ rp, int* __restrict__ sb,
                                                    float* __restrict__ dinv) {
    __shared__ int smem[256];
    __shared__ int red[256];
    int tid = threadIdx.x;
    red[tid] = (tid < blockIdx.x) ? bsum[tid] : 0;   // blockIdx.x <= 78 < 256
    int i = blockIdx.x * 256 + tid;
    int t = (i < N_NODES) ? tot[i] : 0;
    smem[tid] = t;
    __syncthreads();
    for (int off = 128; off > 0; off >>= 1) {
        if (tid < off) red[tid] += red[tid + off];
        __syncthreads();
    }
    for (int off = 1; off < 256; off <<= 1) {
        int x = (tid >= off) ? smem[tid - off] : 0;
        __syncthreads();
        smem[tid] += x;
        __syncthreads();
    }
    if (i < N_NODES) {
        int excl = smem[tid] - t + red[0];
        rp[i] = excl;
        if (i == N_NODES - 1) rp[N_NODES] = excl + t;
        int acc = excl;
        double deg = 1.0;   // self-loop
#pragma unroll
        for (int s = 0; s < NSHARD; s++) {
            unsigned long long p = packed[s * NPAD + i];
            sb[s * NPAD + i] = acc;
            acc += (int)(p >> 48);
            deg += (double)(p & FIX_MASK) * (1.0 / FIX_SCALE);
        }
        dinv[i] = rsqrtf((float)deg);
    }
}

// ---------- K5: atomic-free CSR fill ----------
__global__ __launch_bounds__(256) void k_fill(const int* __restrict__ src,
                                              const int* __restrict__ dst,
                                              const float* __restrict__ ew,
                                              const float* __restrict__ dinv,
                                              const int* __restrict__ sb,
                                              const int* __restrict__ rank,
                                              int2* __restrict__ csr) {
    int e = blockIdx.x * 256 + threadIdx.x;
    int shard = blockIdx.x & (NSHARD - 1);
    if (e < N_EDGES) {
        int s = src[e], d = dst[e];
        int slot = sb[shard * NPAD + d] + rank[e];
        float w = dinv[s] * ew[e] * dinv[d];
        csr[slot] = make_int2(s, __builtin_bit_cast(int, w));
    }
}

// ---------- K6/K8: standalone aggregation — one wave per node, NO barriers ----------
__global__ __launch_bounds__(256) void k_agg(const unsigned char* __restrict__ xw,
                                             short* __restrict__ outb,
                                             const int* __restrict__ rp,
                                             const int2* __restrict__ csr,
                                             const float* __restrict__ dinv,
                                             const float* __restrict__ bias,
                                             int act) {
    int node = blockIdx.x * 4 + (threadIdx.x >> 6);
    int lane = threadIdx.x & 63;
    int half = lane >> 5, l = lane & 31;
    float4 acc = agg_node(node, half, l, xw, rp, csr, dinv);
    if (half == 0) {
        float4 b = ((const float4*)bias)[l];
        acc.x += b.x; acc.y += b.y; acc.z += b.z; acc.w += b.w;
        if (act == 0) {
            acc.x = fmaxf(acc.x, 0.f); acc.y = fmaxf(acc.y, 0.f);
            acc.z = fmaxf(acc.z, 0.f); acc.w = fmaxf(acc.w, 0.f);
        } else {
            acc.x = 1.f / (1.f + __expf(-acc.x)); acc.y = 1.f / (1.f + __expf(-acc.y));
            acc.z = 1.f / (1.f + __expf(-acc.z)); acc.w = 1.f / (1.f + __expf(-acc.w));
        }
        ((uint2*)(outb + (size_t)node * HID))[l] = pack_bf4(acc);
    }
}

// ---------- K7: GEMM h1(bf16) @ W2 -> xw2 (fp8), 16 rows/block ----------
__global__ __launch_bounds__(256) void k_gemm2(const short* __restrict__ Ab,
                                               const short* __restrict__ WT,
                                               unsigned char* __restrict__ Cb) {
    __shared__ short As[16 * 136];
    int tid = threadIdx.x;
    int r0 = blockIdx.x * 16;
    {
        int row = tid >> 4;
        int col0 = (tid & 15) * 8;
        *(bf16x8*)(&As[row * 136 + col0]) = *(const bf16x8*)(Ab + (size_t)(r0 + row) * HID + col0);
    }
    __syncthreads();
    int wave = tid >> 6, lane = tid & 63;
    int m = lane & 15, quad = lane >> 4;
    f32x4 acc[2];
    acc[0] = (f32x4){0.f, 0.f, 0.f, 0.f};
    acc[1] = acc[0];
#pragma unroll
    for (int ks = 0; ks < 4; ks++) {
        int k0 = ks * 32 + quad * 8;
        bf16x8 a = *(const bf16x8*)(&As[m * 136 + k0]);
#pragma unroll
        for (int j = 0; j < 2; j++) {
            int n = (wave * 2 + j) * 16 + m;
            bf16x8 b = *(const bf16x8*)(WT + n * 128 + k0);
            acc[j] = __builtin_amdgcn_mfma_f32_16x16x32_bf16(a, b, acc[j], 0, 0, 0);
        }
    }
#pragma unroll
    for (int j = 0; j < 2; j++) {
        int col = (wave * 2 + j) * 16 + m;
#pragma unroll
        for (int rg = 0; rg < 4; rg++) {
            int grow = r0 + quad * 4 + rg;
            Cb[(size_t)grow * HID + col] = f2fp8(acc[j][rg]);
        }
    }
}

// ---------- K9: fused gate: 32 rows/block (625 blocks), wave owns a 32-col strip ----------
__global__ __launch_bounds__(256) void k_gate(const short* __restrict__ xgb,
                                              const float* __restrict__ hf,
                                              const short* __restrict__ WTu, const short* __restrict__ WTr,
                                              const short* __restrict__ WTc,
                                              const float* __restrict__ pbu, const float* __restrict__ pbr,
                                              const float* __restrict__ pbc,
                                              float* __restrict__ out) {
    __shared__ short Xs[32 * 264];   // [row][0:128]=xg, [128:256]=h (later r*h)
    int tid = threadIdx.x;
    int r0 = blockIdx.x * 32;
#pragma unroll
    for (int i = 0; i < 4; i++) {
        int c = tid + i * 256;       // 1024 bf16x8 chunks
        int row = c >> 5;
        int col0 = (c & 31) * 8;
        int grow = r0 + row;
        bf16x8 v;
        if (col0 < 128) {
            v = *(const bf16x8*)(xgb + (size_t)grow * HID + col0);
        } else {
            const float* p = hf + (size_t)grow * HID + (col0 - 128);
            v = cvt8(*(const float4*)p, *(const float4*)(p + 4));
        }
        *(bf16x8*)(&Xs[row * 264 + col0]) = v;
    }
    __syncthreads();
    int wave = tid >> 6, lane = tid & 63;
    int m = lane & 15, quad = lane >> 4;
    f32x4 au[2][2], ar[2][2];
#pragma unroll
    for (int j = 0; j < 2; j++)
#pragma unroll
        for (int rt = 0; rt < 2; rt++) { au[j][rt] = (f32x4){0.f, 0.f, 0.f, 0.f}; ar[j][rt] = au[j][rt]; }
#pragma unroll
    for (int ks = 0; ks < 8; ks++) {
        int k0 = ks * 32 + quad * 8;
        bf16x8 a0 = *(const bf16x8*)(&Xs[m * 264 + k0]);            // row-tile 0
        bf16x8 a1 = *(const bf16x8*)(&Xs[(16 + m) * 264 + k0]);     // row-tile 1
#pragma unroll
        for (int j = 0; j < 2; j++) {
            int n = (wave * 2 + j) * 16 + m;
            bf16x8 bu_f = *(const bf16x8*)(WTu + n * 256 + k0);
            au[j][0] = __builtin_amdgcn_mfma_f32_16x16x32_bf16(a0, bu_f, au[j][0], 0, 0, 0);
            au[j][1] = __builtin_amdgcn_mfma_f32_16x16x32_bf16(a1, bu_f, au[j][1], 0, 0, 0);
            bf16x8 br_f = *(const bf16x8*)(WTr + n * 256 + k0);
            ar[j][0] = __builtin_amdgcn_mfma_f32_16x16x32_bf16(a0, br_f, ar[j][0], 0, 0, 0);
            ar[j][1] = __builtin_amdgcn_mfma_f32_16x16x32_bf16(a1, br_f, ar[j][1], 0, 0, 0);
        }
    }
    __syncthreads();   // phase-1 reads of the h half must finish before overwrite
#pragma unroll
    for (int j = 0; j < 2; j++) {
        int col = (wave * 2 + j) * 16 + m;
        float brv = pbr[col];
#pragma unroll
        for (int rt = 0; rt < 2; rt++) {
#pragma unroll
            for (int rg = 0; rg < 4; rg++) {
                int trow = rt * 16 + quad * 4 + rg;
                float rv = 1.f / (1.f + __expf(-(ar[j][rt][rg] + brv)));
                float hv = bf2f(Xs[trow * 264 + 128 + col]);
                Xs[trow * 264 + 128 + col] = f2bf(rv * hv);
            }
        }
    }
    __syncthreads();
    f32x4 ac[2][2];
#pragma unroll
    for (int j = 0; j < 2; j++)
#pragma unroll
        for (int rt = 0; rt < 2; rt++) ac[j][rt] = (f32x4){0.f, 0.f, 0.f, 0.f};
#pragma unroll
    for (int ks = 0; ks < 8; ks++) {
        int k0 = ks * 32 + quad * 8;
        bf16x8 a0 = *(const bf16x8*)(&Xs[m * 264 + k0]);
        bf16x8 a1 = *(const bf16x8*)(&Xs[(16 + m) * 264 + k0]);
#pragma unroll
        for (int j = 0; j < 2; j++) {
            int n = (wave * 2 + j) * 16 + m;
            bf16x8 bc_f = *(const bf16x8*)(WTc + n * 256 + k0);
            ac[j][0] = __builtin_amdgcn_mfma_f32_16x16x32_bf16(a0, bc_f, ac[j][0], 0, 0, 0);
            ac[j][1] = __builtin_amdgcn_mfma_f32_16x16x32_bf16(a1, bc_f, ac[j][1], 0, 0, 0);
        }
    }
#pragma unroll
    for (int j = 0; j < 2; j++) {
        int col = (wave * 2 + j) * 16 + m;
        float buv = pbu[col], bcv = pbc[col];
#pragma unroll
        for (int rt = 0; rt < 2; rt++) {
#pragma unroll
            for (int rg = 0; rg < 4; rg++) {
                int grow = r0 + rt * 16 + quad * 4 + rg;
                float uv = 1.f / (1.f + __expf(-(au[j][rt][rg] + buv)));
                float cv = tanhf(ac[j][rt][rg] + bcv);
                float hv = hf[(size_t)grow * HID + col];
                out[(size_t)grow * HID + col] = uv * hv + (1.f - uv) * cv;
            }
        }
    }
}

extern "C" void kernel_launch(void* const* d_in, const int* in_sizes, int n_in,
                              void* d_out, int out_size, void* d_ws, size_t ws_size,
                              hipStream_t stream) {
    const float* x  = (const float*)d_in[0];
    const int*   ei = (const int*)d_in[1];
    const float* ew = (const float*)d_in[2];
    const float* h  = (const float*)d_in[3];
    const float* W1 = (const float*)d_in[4];
    const float* b1 = (const float*)d_in[5];
    const float* W2 = (const float*)d_in[6];
    const float* b2 = (const float*)d_in[7];
    const float* Wu = (const float*)d_in[8];
    const float* bu = (const float*)d_in[9];
    const float* Wr = (const float*)d_in[10];
    const float* br = (const float*)d_in[11];
    const float* Wc = (const float*)d_in[12];
    const float* bc = (const float*)d_in[13];
    const int* src = ei;
    const int* dst = ei + N_EDGES;
    float* out = (float*)d_out;

    const size_t NH = (size_t)N_NODES * HID;
    float* ws = (float*)d_ws;
    float* dinv = ws;                                            // NPAD f32
    int*   rp   = (int*)(ws + NPAD);                             // NPAD
    unsigned long long* packed = (unsigned long long*)(ws + 2 * NPAD);  // 8*NPAD u64 = 16*NPAD f32
    int*   sb   = (int*)(ws + 18 * NPAD);                        // 8*NPAD
    int*   tot  = (int*)(ws + 26 * NPAD);                        // NPAD
    int*   bsum = (int*)(ws + 27 * NPAD);                        // 128
    int*   rank = (int*)(ws + 27 * NPAD + 128);                  // N_EDGES
    int2*  csr  = (int2*)(ws + 27 * NPAD + 128 + N_EDGES);       // N_EDGES int2
    unsigned char* xw  = (unsigned char*)(ws + 27 * NPAD + 128 + 3 * N_EDGES);  // NH fp8
    unsigned char* xw2 = xw + NH;                                // NH fp8
    short* h1b = (short*)(xw2 + NH);                             // NH bf16
    short* xgb = h1b + NH;                                       // NH bf16
    short* WT1 = xgb + NH;
    short* WT2 = WT1 + 16384;
    short* WTu = WT2 + 16384;
    short* WTr = WTu + 32768;
    short* WTc = WTr + 32768;

    // K1: weight cvt + packed init (co-scheduled)
    k_prep<<<512 + (NSHARD * NPAD + 255) / 256, 256, 0, stream>>>(
        W1, W2, Wu, Wr, Wc, WT1, WT2, WTu, WTr, WTc, packed);
    // K2: hist + layer-1 GEMM (co-scheduled)
    k_hist_gemm<<<2500 + N_NODES / 16, 256, 0, stream>>>(packed, rank, dst, ew, x, WT1, xw);
    // K3/K4: scan -> rp, sb, dinv
    k_scan_part<<<NBLK, 256, 0, stream>>>(packed, tot, bsum);
    k_scan_final<<<NBLK, 256, 0, stream>>>(packed, tot, bsum, rp, sb, dinv);
    // K5: CSR fill
    k_fill<<<N_EDGES / 256, 256, 0, stream>>>(src, dst, ew, dinv, sb, rank, csr);
    // K6: aggregate layer 1 (ReLU) -> h1 bf16 (pipelined gather)
    k_agg<<<N_NODES / 4, 256, 0, stream>>>(xw, h1b, rp, csr, dinv, b1, 0);
    // K7: GEMM h1 @ W2 -> xw2 fp8
    k_gemm2<<<N_NODES / 16, 256, 0, stream>>>(h1b, WT2, xw2);
    // K8: aggregate layer 2 (sigmoid) -> xg bf16 (pipelined gather)
    k_agg<<<N_NODES / 4, 256, 0, stream>>>(xw2, xgb, rp, csr, dinv, b2, 1);
    // K9: fused gating -> out (32 rows/block)
    k_gate<<<N_NODES / 32, 256, 0, stream>>>(xgb, h, WTu, WTr, WTc, bu, br, bc, out);
}